// Round 5
// baseline (432.568 us; speedup 1.0000x reference)
//
#include <hip/hip_runtime.h>

// Lyapunov spectrum via chunked QR scan with warm-up re-convergence.
// inp: (T=4096, 9, B=2048) fp32.  out: (3, B) fp32.
// R5: 4 batches/thread via float4 loads -> each wave load = 1 KB contiguous
//     (R4's 256 B chunks pinned effective HBM BW at ~4 TB/s; bigger DRAM
//     bursts are the theory). NCHUNK=128, WARM=24, PF=2 register ring,
//     ILP=4 GS chains per thread. 1024 waves (1/SIMD).

typedef float v4 __attribute__((ext_vector_type(4)));

constexpr int T_STEPS = 4096;
constexpr int BATCH   = 2048;
constexpr int NCHUNK  = 128;
constexpr int KSEG    = T_STEPS / NCHUNK;  // 32
constexpr int WARM    = 24;
constexpr int PF      = 2;                 // ring depth (VGPR-bounded: Jb = 72 regs)

constexpr int COLV4   = BATCH / 4;         // 512 v4 per m column
constexpr int ROWV4   = 9 * COLV4;         // 4608 v4 per time step

__device__ __forceinline__ v4 rsq4(v4 x) {
    v4 r;
    r.x = __builtin_amdgcn_rsqf(x.x);
    r.y = __builtin_amdgcn_rsqf(x.y);
    r.z = __builtin_amdgcn_rsqf(x.z);
    r.w = __builtin_amdgcn_rsqf(x.w);
    return r;
}

__device__ __forceinline__ void lya_step(const v4 J[9], v4 Q[9], v4 d[3]) {
    // M = J * Q : four independent 3x3 systems in the v4 lanes
    v4 M[9];
#pragma unroll
    for (int i = 0; i < 3; ++i) {
#pragma unroll
        for (int j = 0; j < 3; ++j) {
            M[i * 3 + j] = J[i * 3 + 0] * Q[0 * 3 + j]
                         + J[i * 3 + 1] * Q[1 * 3 + j]
                         + J[i * 3 + 2] * Q[2 * 3 + j];
        }
    }
    // Classical Gram-Schmidt (projections vs original cols), 1/d = rsq^2
    v4 b0x = M[0], b0y = M[3], b0z = M[6];
    v4 d00 = b0x * b0x + b0y * b0y + b0z * b0z;
    v4 r0 = rsq4(d00);
    v4 inv00 = r0 * r0;

    v4 x1x = M[1], x1y = M[4], x1z = M[7];
    v4 c01 = (b0x * x1x + b0y * x1y + b0z * x1z) * inv00;
    v4 b1x = x1x - c01 * b0x;
    v4 b1y = x1y - c01 * b0y;
    v4 b1z = x1z - c01 * b0z;
    v4 d11 = b1x * b1x + b1y * b1y + b1z * b1z;
    v4 r1 = rsq4(d11);
    v4 inv11 = r1 * r1;

    v4 x2x = M[2], x2y = M[5], x2z = M[8];
    v4 c02 = (b0x * x2x + b0y * x2y + b0z * x2z) * inv00;
    v4 c12 = (b1x * x2x + b1y * x2y + b1z * x2z) * inv11;
    v4 b2x = x2x - c02 * b0x - c12 * b1x;
    v4 b2y = x2y - c02 * b0y - c12 * b1y;
    v4 b2z = x2z - c02 * b0z - c12 * b1z;
    v4 d22 = b2x * b2x + b2y * b2y + b2z * b2z;
    v4 r2 = rsq4(d22);

    Q[0] = b0x * r0; Q[3] = b0y * r0; Q[6] = b0z * r0;
    Q[1] = b1x * r1; Q[4] = b1y * r1; Q[7] = b1z * r1;
    Q[2] = b2x * r2; Q[5] = b2y * r2; Q[8] = b2z * r2;
    d[0] = d00; d[1] = d11; d[2] = d22;
}

__global__ __launch_bounds__(256) void lya_kernel(const float* __restrict__ inp,
                                                  float* __restrict__ out) {
    const int tid   = blockIdx.x * 256 + threadIdx.x;
    const int l     = tid & (COLV4 - 1);   // thread-in-chunk: batches 4l..4l+3
    const int chunk = tid >> 9;            // 512 threads/chunk -> wave-uniform
    const int kacc  = chunk * KSEG;
    const int s0    = (kacc >= WARM) ? (kacc - WARM) : 0;
    const int nwarm = kacc - s0;           // 0 (chunk 0) or WARM

    const v4* __restrict__ base = (const v4*)inp;

    v4 one  = {1.f, 1.f, 1.f, 1.f};
    v4 zero = {0.f, 0.f, 0.f, 0.f};
    v4 Q[9] = {one, zero, zero,
               zero, one, zero,
               zero, zero, one};
    v4 acc0 = zero, acc1 = zero, acc2 = zero;

    // Preload ring: steps s0, s0+1 (<= 4041 < 4096).
    v4 Jb[PF][9];
#pragma unroll
    for (int r = 0; r < PF; ++r) {
        const v4* p = base + (size_t)(s0 + r) * ROWV4 + l;
#pragma unroll
        for (int m = 0; m < 9; ++m) Jb[r][m] = p[(size_t)m * COLV4];
    }

    v4 d[3];

    // Warm-up: re-converge Q, discard log-norms. Prefetch t = s0+i+r+PF
    // (max kacc+1 < 4096, always in range).
    for (int i = 0; i < nwarm; i += PF) {
#pragma unroll
        for (int r = 0; r < PF; ++r) {
            lya_step(Jb[r], Q, d);
            const v4* p = base + (size_t)(s0 + i + r + PF) * ROWV4 + l;
#pragma unroll
            for (int m = 0; m < 9; ++m) Jb[r][m] = p[(size_t)m * COLV4];
        }
    }

    // Accumulation: product over PF steps, then one log2 per column component.
    for (int i = nwarm; i < nwarm + KSEG; i += PF) {
        v4 p0 = one, p1 = one, p2 = one;
#pragma unroll
        for (int r = 0; r < PF; ++r) {
            lya_step(Jb[r], Q, d);
            p0 *= d[0]; p1 *= d[1]; p2 *= d[2];
            int tp = s0 + i + r + PF;
            if (tp > T_STEPS - 1) tp = T_STEPS - 1;   // tail: clamped redundant read
            const v4* p = base + (size_t)tp * ROWV4 + l;
#pragma unroll
            for (int m = 0; m < 9; ++m) Jb[r][m] = p[(size_t)m * COLV4];
        }
        acc0.x += __log2f(p0.x); acc0.y += __log2f(p0.y);
        acc0.z += __log2f(p0.z); acc0.w += __log2f(p0.w);
        acc1.x += __log2f(p1.x); acc1.y += __log2f(p1.y);
        acc1.z += __log2f(p1.z); acc1.w += __log2f(p1.w);
        acc2.x += __log2f(p2.x); acc2.y += __log2f(p2.y);
        acc2.z += __log2f(p2.z); acc2.w += __log2f(p2.w);
    }

    // log||b|| = 0.5*ln2*log2(d);  Lya = sum / (T*dt)
    const float scale = 0.5f * 0.69314718056f / (T_STEPS * 0.01f);
    const int b0 = l * 4;
#pragma unroll
    for (int j = 0; j < 4; ++j) {
        atomicAdd(&out[0 * BATCH + b0 + j], ((const float*)&acc0)[j] * scale);
        atomicAdd(&out[1 * BATCH + b0 + j], ((const float*)&acc1)[j] * scale);
        atomicAdd(&out[2 * BATCH + b0 + j], ((const float*)&acc2)[j] * scale);
    }
}

extern "C" void kernel_launch(void* const* d_in, const int* in_sizes, int n_in,
                              void* d_out, int out_size, void* d_ws, size_t ws_size,
                              hipStream_t stream) {
    const float* inp = (const float*)d_in[0];
    float* out = (float*)d_out;

    hipMemsetAsync(out, 0, (size_t)out_size * sizeof(float), stream);

    // NCHUNK * COLV4 threads = 65536 -> 256 blocks of 256 -> 1024 waves.
    dim3 grid(NCHUNK * COLV4 / 256);
    dim3 block(256);
    lya_kernel<<<grid, block, 0, stream>>>(inp, out);
}